// Round 14
// baseline (75.603 us; speedup 1.0000x reference)
//
#include <hip/hip_runtime.h>
#include <hip/hip_bf16.h>
#include <hip/hip_fp16.h>
#include <math.h>

// DCNv2 forward, fully fused, f16 pipeline, 2-deep software-pipelined Phase B:
// per block stage a 6x36-pixel NHWC f16 window in LDS (XOR-swizzled); aux conv
// (f16 MFMA) -> oml (pixel-major f16) in LDS; main loop alternates named
// register sets: STAGE(k+1) issues geometry + 8 corner ds_read_b128 (pinned
// above CONSUME(k) by sched_barrier) so tap k's bilinear+MFMA runs under tap
// k+1's LDS latency. Bilinear is packed f16 (v_pk_fma_f16) straight into MFMA
// A-fragments (D = V*W^T). Rare exec-masked global fallback for big offsets.
// Tile = 2 rows x 32 cols, 4 waves. x [4,64,192,192] f32 -> out same shape.

#define NB   4
#define CIN  64
#define COUT 64
#define HH   192
#define WW   192
#define HW   (HH*WW)

typedef __attribute__((ext_vector_type(4))) float f32x4;
typedef __attribute__((ext_vector_type(8))) _Float16 f16x8;
typedef __attribute__((ext_vector_type(4))) unsigned int u32x4;

__device__ __forceinline__ int iclamp(int v, int lo, int hi) {
    return v < lo ? lo : (v > hi ? hi : v);
}
__device__ __forceinline__ unsigned short f16bits(float f) {
    __half h = __float2half(f);
    union { __half h; unsigned short u; } t; t.h = h; return t.u;
}
__device__ __forceinline__ float h2f(unsigned short u) {
    union { unsigned short u; __half h; } t; t.u = u; return __half2float(t.h);
}

// ---------------------------------------------------------------------------
// Kernel A: x f32 NCHW -> xt f16 NHWC (128 B per pixel).
// ---------------------------------------------------------------------------
__global__ __launch_bounds__(256) void to_nhwc(
        const float* __restrict__ x, unsigned short* __restrict__ xt) {
    int n  = blockIdx.y;
    int px = blockIdx.x * 256 + threadIdx.x;     // 0..HW-1
    const float* xn = x + (size_t)n * CIN * HW + px;
    union { unsigned short us[64]; u32x4 q[8]; } pk;
#pragma unroll
    for (int c = 0; c < 64; c++) pk.us[c] = f16bits(xn[c * HW]);
    u32x4* dst = (u32x4*)(xt + ((size_t)n * HW + px) * 64);
#pragma unroll
    for (int i = 0; i < 8; i++) dst[i] = pk.q[i];
}

// ---------------------------------------------------------------------------
// Kernel 0: weight repack into MFMA fragment order (f16 bits).
//  wfrag (main): idx = (((k*4+nf)*2+kc)*64 + l)*8 + j
//  wauxf (aux, 32 out-ch padded from 27): idx = ((k*4 + ga*2 + kc)*64 + l)*8 + j
//  baux  f32[32]: b_off | b_mod | 0
// ---------------------------------------------------------------------------
__global__ __launch_bounds__(256) void prep_weights(
        const float* __restrict__ w, const float* __restrict__ w_off,
        const float* __restrict__ w_mod, const float* __restrict__ b_off,
        const float* __restrict__ b_mod, unsigned short* __restrict__ wfrag,
        unsigned short* __restrict__ wauxf, float* __restrict__ baux) {
    int idx = blockIdx.x * 256 + threadIdx.x;
    if (idx < 36864) {
        int j    = idx & 7;
        int lane = (idx >> 3) & 63;
        int kc   = (idx >> 9) & 1;
        int g    = (idx >> 10) & 3;
        int k    = idx >> 12;
        int o = g * 16 + (lane & 15);
        int c = kc * 32 + (lane >> 4) * 8 + j;
        wfrag[idx] = f16bits(w[(o * 64 + c) * 9 + k]);
    }
    if (idx < 18432) {
        int j    = idx & 7;
        int lane = (idx >> 3) & 63;
        int kc   = (idx >> 9) & 1;
        int ga   = (idx >> 10) & 1;
        int k    = idx >> 11;
        int o = ga * 16 + (lane & 15);
        int c = kc * 32 + (lane >> 4) * 8 + j;
        float v = 0.f;
        if (o < 18)      v = w_off[(o * 64 + c) * 9 + k];
        else if (o < 27) v = w_mod[((o - 18) * 64 + c) * 9 + k];
        wauxf[idx] = f16bits(v);
    }
    if (idx < 32) {
        float v = 0.f;
        if (idx < 18)      v = b_off[idx];
        else if (idx < 27) v = b_mod[idx - 18];
        baux[idx] = v;
    }
}

union Qreg { u32x4 u; __half2 h2[4]; };

// --- STAGE(k): oml read -> geometry -> weights (packed half2) + 8 corner
//     ds_read_b128 into named Q set; rare global fallback.
#define STAGE(K, WT, Q) do {                                                  \
    int k_ = (K);                                                             \
    int ky_ = k_ / 3, kx_ = k_ - 3 * (k_ / 3);                                \
    unsigned int oyx_ = *(const unsigned int*)(omp + 2 * k_);                 \
    float offy_ = h2f((unsigned short)(oyx_ & 0xffffu));                      \
    float offx_ = h2f((unsigned short)(oyx_ >> 16));                          \
    float mm_   = h2f(omp[18 + k_]);                                          \
    float py_  = offy_ + (float)(ho_w - 1 + ky_);                             \
    float pxf_ = offx_ + (float)(wox - 1 + kx_);                              \
    float y0f_ = floorf(py_), x0f_ = floorf(pxf_);                            \
    float ly_ = py_ - y0f_, lx_ = pxf_ - x0f_;                                \
    int y0_ = (int)y0f_, x0_ = (int)x0f_;                                     \
    int y1_ = y0_ + 1, x1_ = x0_ + 1;                                         \
    bool y0ok_ = (unsigned)y0_ < (unsigned)HH, y1ok_ = (unsigned)y1_ < (unsigned)HH; \
    bool x0ok_ = (unsigned)x0_ < (unsigned)WW, x1ok_ = (unsigned)x1_ < (unsigned)WW; \
    float wt0_ = (y0ok_ && x0ok_) ? mm_ * (1.f - ly_) * (1.f - lx_) : 0.f;    \
    float wt1_ = (y0ok_ && x1ok_) ? mm_ * (1.f - ly_) * lx_         : 0.f;    \
    float wt2_ = (y1ok_ && x0ok_) ? mm_ * ly_ * (1.f - lx_)         : 0.f;    \
    float wt3_ = (y1ok_ && x1ok_) ? mm_ * ly_ * lx_                 : 0.f;    \
    WT[0] = __float2half2_rn(wt0_);                                           \
    WT[1] = __float2half2_rn(wt1_);                                           \
    WT[2] = __float2half2_rn(wt2_);                                           \
    WT[3] = __float2half2_rn(wt3_);                                           \
    int y0c_ = iclamp(y0_, 0, HH - 1), y1c_ = iclamp(y1_, 0, HH - 1);         \
    int x0c_ = iclamp(x0_, 0, WW - 1), x1c_ = iclamp(x1_, 0, WW - 1);         \
    int sy0_ = y0c_ - ho2 + 2,    sy1_ = y1c_ - ho2 + 2;                      \
    int sx0_ = x0c_ - wobase + 2, sx1_ = x1c_ - wobase + 2;                   \
    int sy0c_ = iclamp(sy0_, 0, 5),  sy1c_ = iclamp(sy1_, 0, 5);              \
    int sx0c_ = iclamp(sx0_, 0, 35), sx1c_ = iclamp(sx1_, 0, 35);             \
    bool fb00_ = (wt0_ > 0.f) && ((sy0_ != sy0c_) | (sx0_ != sx0c_));         \
    bool fb01_ = (wt1_ > 0.f) && ((sy0_ != sy0c_) | (sx1_ != sx1c_));         \
    bool fb10_ = (wt2_ > 0.f) && ((sy1_ != sy1c_) | (sx0_ != sx0c_));         \
    bool fb11_ = (wt3_ > 0.f) && ((sy1_ != sy1c_) | (sx1_ != sx1c_));         \
    int s00_ = sy0c_ * 36 + sx0c_, s01_ = sy0c_ * 36 + sx1c_;                 \
    int s10_ = sy1c_ * 36 + sx0c_, s11_ = sy1c_ * 36 + sx1c_;                 \
    const char* w00_ = (const char*)win + s00_ * 128;                         \
    const char* w01_ = (const char*)win + s01_ * 128;                         \
    const char* w10_ = (const char*)win + s10_ * 128;                         \
    const char* w11_ = (const char*)win + s11_ * 128;                         \
    int x00_ = (s00_ & 7) << 4, x01_ = (s01_ & 7) << 4;                       \
    int x10_ = (s10_ & 7) << 4, x11_ = (s11_ & 7) << 4;                       \
    Q[0].u = *(const u32x4*)(w00_ + ((cb0)      ^ x00_));                     \
    Q[1].u = *(const u32x4*)(w00_ + ((cb0 + 64) ^ x00_));                     \
    Q[2].u = *(const u32x4*)(w01_ + ((cb0)      ^ x01_));                     \
    Q[3].u = *(const u32x4*)(w01_ + ((cb0 + 64) ^ x01_));                     \
    Q[4].u = *(const u32x4*)(w10_ + ((cb0)      ^ x10_));                     \
    Q[5].u = *(const u32x4*)(w10_ + ((cb0 + 64) ^ x10_));                     \
    Q[6].u = *(const u32x4*)(w11_ + ((cb0)      ^ x11_));                     \
    Q[7].u = *(const u32x4*)(w11_ + ((cb0 + 64) ^ x11_));                     \
    if (__builtin_expect(fb00_ | fb01_ | fb10_ | fb11_, 0)) {                 \
        if (fb00_) { const char* gp = xb + ((size_t)y0c_ * WW + x0c_) * 128 + cb0; \
                     Q[0].u = *(const u32x4*)gp; Q[1].u = *(const u32x4*)(gp + 64); } \
        if (fb01_) { const char* gp = xb + ((size_t)y0c_ * WW + x1c_) * 128 + cb0; \
                     Q[2].u = *(const u32x4*)gp; Q[3].u = *(const u32x4*)(gp + 64); } \
        if (fb10_) { const char* gp = xb + ((size_t)y1c_ * WW + x0c_) * 128 + cb0; \
                     Q[4].u = *(const u32x4*)gp; Q[5].u = *(const u32x4*)(gp + 64); } \
        if (fb11_) { const char* gp = xb + ((size_t)y1c_ * WW + x1c_) * 128 + cb0; \
                     Q[6].u = *(const u32x4*)gp; Q[7].u = *(const u32x4*)(gp + 64); } \
    }                                                                         \
} while (0)

// --- CONSUME(k): weight B-fragments + packed f16 bilinear + 8 MFMA.
#define CONSUME(K, WT, Q) do {                                                \
    int k_ = (K);                                                             \
    const f16x8* wfk_ = ((const f16x8*)wfrag) + (k_ * 8) * 64 + l;            \
    f16x8 wB_[8];                                                             \
    _Pragma("unroll")                                                         \
    for (int f_ = 0; f_ < 8; ++f_) wB_[f_] = wfk_[f_ * 64];                   \
    union { __half2 h2[4]; f16x8 v; } fA0_, fA1_;                             \
    _Pragma("unroll")                                                         \
    for (int j_ = 0; j_ < 4; ++j_) {                                          \
        __half2 t_ = __hmul2(Q[0].h2[j_], WT[0]);                             \
        t_ = __hfma2(Q[2].h2[j_], WT[1], t_);                                 \
        t_ = __hfma2(Q[4].h2[j_], WT[2], t_);                                 \
        t_ = __hfma2(Q[6].h2[j_], WT[3], t_);                                 \
        fA0_.h2[j_] = t_;                                                     \
        __half2 s_ = __hmul2(Q[1].h2[j_], WT[0]);                             \
        s_ = __hfma2(Q[3].h2[j_], WT[1], s_);                                 \
        s_ = __hfma2(Q[5].h2[j_], WT[2], s_);                                 \
        s_ = __hfma2(Q[7].h2[j_], WT[3], s_);                                 \
        fA1_.h2[j_] = s_;                                                     \
    }                                                                         \
    __builtin_amdgcn_s_setprio(1);                                            \
    _Pragma("unroll")                                                         \
    for (int nf_ = 0; nf_ < 4; ++nf_) {                                       \
        acc[nf_] = __builtin_amdgcn_mfma_f32_16x16x32_f16(fA0_.v, wB_[nf_ * 2],     acc[nf_], 0, 0, 0); \
        acc[nf_] = __builtin_amdgcn_mfma_f32_16x16x32_f16(fA1_.v, wB_[nf_ * 2 + 1], acc[nf_], 0, 0, 0); \
    }                                                                         \
    __builtin_amdgcn_s_setprio(0);                                            \
} while (0)

// ---------------------------------------------------------------------------
// Fused kernel. Tile = 2 output rows x 32 cols. 4 waves: wave = (r2<<1)|g2.
// Window: 6 rows x 36 cols, 128 B/slot, XOR-swizzled. LDS = 27648 + 4096 B.
// ---------------------------------------------------------------------------
__global__ __launch_bounds__(256, 3) void dcn_fused(
        const unsigned short* __restrict__ xt,
        const unsigned short* __restrict__ wfrag,
        const unsigned short* __restrict__ wauxf,
        const float* __restrict__ baux,
        const float* __restrict__ bias,
        float* __restrict__ out) {
    __shared__ __align__(16) unsigned short win[216 * 64];  // 27648 B
    __shared__ __align__(16) unsigned short oml[2][32][32]; // 4096 B, pixel-major

    int tid = threadIdx.x;
    int l   = tid & 63;
    int wv  = __builtin_amdgcn_readfirstlane(tid >> 6);   // 0..3
    int r2  = wv >> 1;        // output row within tile
    int g2  = wv & 1;         // 16-px half within row

    int id = blockIdx.x;                        // 0..2303
    int sw = (id & 7) * 288 + (id >> 3);        // bijective XCD swizzle
    int n  = sw / 576;
    int r  = sw % 576;
    int ho2    = (r / 6) * 2;
    int wobase = (r % 6) * 32;

    const char* xb = (const char*)xt + (size_t)n * HW * 128;

    // ---------------- stage the 6x36 window into LDS (swizzled) ----------
    if (tid < 216) {
        int rw = tid / 36, cl = tid - rw * 36;
        int gy = iclamp(ho2 - 2 + rw, 0, HH - 1);
        int gx = iclamp(wobase - 2 + cl, 0, WW - 1);
        const u32x4* src = (const u32x4*)(xb + ((size_t)gy * WW + gx) * 128);
        char* dst = (char*)win + tid * 128;
        int xw = (tid & 7) << 4;
#pragma unroll
        for (int c = 0; c < 8; c++)
            *(u32x4*)(dst + ((c * 16) ^ xw)) = src[c];
    }
    __syncthreads();

    // ================= Phase A: aux conv for this tile =================
    {
        f32x4 aacc[2];
        aacc[0] = (f32x4){0.f, 0.f, 0.f, 0.f};
        aacc[1] = (f32x4){0.f, 0.f, 0.f, 0.f};
        const f16x8 zero8 = (f16x8){0, 0, 0, 0, 0, 0, 0, 0};
        int pa   = g2 * 16 + (l & 15);          // px in row, 0..31
        int cba  = (l >> 4) * 16;               // 8-ch chunk byte offset
        int ho_a = ho2 + r2;

#pragma unroll 1
        for (int k = 0; k < 9; k++) {
            int ky = k / 3, kx = k - 3 * (k / 3);
            int ys = ho_a + ky - 1;
            if ((unsigned)ys >= (unsigned)HH) continue;   // uniform row skip
            int xs = wobase + pa + kx - 1;
            bool ok = (unsigned)xs < (unsigned)WW;
            int sA = (ky + 1 + r2) * 36 + (pa + kx + 1);  // window slot
            const char* pp = (const char*)win + sA * 128;
            int xw = (sA & 7) << 4;
            const f16x8* wa = ((const f16x8*)wauxf) + (k * 4) * 64 + l;
#pragma unroll
            for (int kc = 0; kc < 2; kc++) {
                f16x8 bv = *(const f16x8*)(pp + ((kc * 64 + cba) ^ xw));
                if (!ok) bv = zero8;
                f16x8 a0 = wa[(kc)     * 64];      // o 0..15
                f16x8 a1 = wa[(2 + kc) * 64];      // o 16..31
                aacc[0] = __builtin_amdgcn_mfma_f32_16x16x32_f16(a0, bv, aacc[0], 0, 0, 0);
                aacc[1] = __builtin_amdgcn_mfma_f32_16x16x32_f16(a1, bv, aacc[1], 0, 0, 0);
            }
        }
#pragma unroll
        for (int h = 0; h < 2; h++) {
#pragma unroll
            for (int rr = 0; rr < 4; rr++) {
                int o = h * 16 + (l >> 4) * 4 + rr;
                float v = aacc[h][rr] + baux[o];
                if (o >= 18) v = 2.f / (1.f + expf(-v));
                oml[r2][pa][o] = f16bits(v);      // pixel-major
            }
        }
    }
    __syncthreads();   // window + oml ready; no further barriers

    // ================= Phase B: deform sample + main conv =================
    f32x4 acc[4];
#pragma unroll
    for (int nf = 0; nf < 4; nf++) acc[nf] = (f32x4){0.f, 0.f, 0.f, 0.f};

    int p_loc = l & 15;             // pixel within wave's 16 (M-row)
    int chunk = l >> 4;             // K-chunk 0..3
    int p     = g2 * 16 + p_loc;    // pixel in row, 0..31
    int ho_w  = ho2 + r2;
    int wox   = wobase + p;         // global wo of this pixel
    int cb0   = chunk * 16;         // chunk byte offset within pixel line
    const unsigned short* omp = &oml[r2][p][0];

    __half2 wtA[4], wtB[4];
    Qreg qA[8], qB[8];

    STAGE(0, wtA, qA);
#pragma unroll 1
    for (int kk = 0; kk < 4; ++kk) {
        int k1 = 2 * kk + 1;
        int k2 = 2 * kk + 2;
        STAGE(k1, wtB, qB);                      // prefetch tap 2kk+1
        __builtin_amdgcn_sched_barrier(0);       // pin issue above consume
        CONSUME(2 * kk, wtA, qA);                // finish tap 2kk
        STAGE(k2, wtA, qA);                      // prefetch tap 2kk+2 (k2==8 last)
        __builtin_amdgcn_sched_barrier(0);
        CONSUME(k1, wtB, qB);                    // finish tap 2kk+1
    }
    CONSUME(8, wtA, qA);

    // epilogue: D map row=(l>>4)*4+rr = pixel-in-wave, col=l&15 = o-in-tile
    // out lines: full 128-B lines per block (r12 lesson).
#pragma unroll
    for (int nf = 0; nf < 4; nf++) {
        int o = nf * 16 + p_loc;
        float bo = bias[o];
        int wo = wobase + g2 * 16 + chunk * 4;
        float* op = out + (((size_t)n * COUT + o) * HH + ho_w) * WW + wo;
#pragma unroll
        for (int rr = 0; rr < 4; rr++) {
            float v = acc[nf][rr] + bo;
            op[rr] = fmaxf(v, 0.f);
        }
    }
}

// ---------------------------------------------------------------------------
extern "C" void kernel_launch(void* const* d_in, const int* in_sizes, int n_in,
                              void* d_out, int out_size, void* d_ws, size_t ws_size,
                              hipStream_t stream) {
    const float* x     = (const float*)d_in[0];
    const float* w_off = (const float*)d_in[1];
    const float* b_off = (const float*)d_in[2];
    const float* w_mod = (const float*)d_in[3];
    const float* b_mod = (const float*)d_in[4];
    const float* w     = (const float*)d_in[5];
    const float* b     = (const float*)d_in[6];
    float* out = (float*)d_out;

    // ws layout: wfrag f16[36864] | wauxf f16[18432] | baux f32[32] |
    //            xt f16 NHWC [4*HW*64]                       (~19 MB)
    unsigned short* wfrag = (unsigned short*)d_ws;
    unsigned short* wauxf = wfrag + 36864;
    float* baux = (float*)(wauxf + 18432);
    unsigned short* xt = (unsigned short*)(baux + 32);

    to_nhwc<<<dim3(144, NB), dim3(256), 0, stream>>>(x, xt);
    prep_weights<<<dim3(144), dim3(256), 0, stream>>>(w, w_off, w_mod, b_off,
                                                      b_mod, wfrag, wauxf, baux);
    dcn_fused<<<dim3(2304), dim3(256), 0, stream>>>(xt, wfrag, wauxf, baux, b, out);
}

// Round 15
// 72.427 us; speedup vs baseline: 1.0439x; 1.0439x over previous
//
#include <hip/hip_runtime.h>
#include <hip/hip_bf16.h>
#include <hip/hip_fp16.h>
#include <math.h>

// DCNv2 forward, fully fused, f16 pipeline with PLAN precompute:
//  stage 6x36 NHWC f16 window in LDS (XOR-swizzled) ->
//  Phase A: aux conv (f16 MFMA) -> oml (pixel-major f16) in LDS ->
//  Phase P: per (row,px,tap) compute bilinear weights + 4 corner codes ONCE
//           (576 plans, ~2.25/thread) -> planW/planC in LDS ->
//  Phase B: rolled 9-tap loop; per lane: 2 plan ds_reads, cheap addr math,
//           8 corner ds_read_b128, packed-f16 bilinear straight into MFMA
//           A-fragments (D = V*W^T), 8 MFMA. Rare global fallback via c<0.
// Tile = 2 rows x 32 cols, 4 waves, 50.2 KB LDS (3 blocks/CU).
// x [4,64,192,192] f32 -> out same shape.

#define NB   4
#define CIN  64
#define COUT 64
#define HH   192
#define WW   192
#define HW   (HH*WW)

typedef __attribute__((ext_vector_type(4))) float f32x4;
typedef __attribute__((ext_vector_type(8))) _Float16 f16x8;
typedef __attribute__((ext_vector_type(4))) unsigned int u32x4;
typedef __attribute__((ext_vector_type(4))) int i32x4;

__device__ __forceinline__ int iclamp(int v, int lo, int hi) {
    return v < lo ? lo : (v > hi ? hi : v);
}
__device__ __forceinline__ unsigned short f16bits(float f) {
    __half h = __float2half(f);
    union { __half h; unsigned short u; } t; t.h = h; return t.u;
}
__device__ __forceinline__ float h2f(unsigned short u) {
    union { unsigned short u; __half h; } t; t.u = u; return __half2float(t.h);
}
__device__ __forceinline__ unsigned int dup16(float f) {
    unsigned int b = f16bits(f);
    return b | (b << 16);
}

// ---------------------------------------------------------------------------
// Kernel A: x f32 NCHW -> xt f16 NHWC (128 B per pixel).
// ---------------------------------------------------------------------------
__global__ __launch_bounds__(256) void to_nhwc(
        const float* __restrict__ x, unsigned short* __restrict__ xt) {
    int n  = blockIdx.y;
    int px = blockIdx.x * 256 + threadIdx.x;     // 0..HW-1
    const float* xn = x + (size_t)n * CIN * HW + px;
    union { unsigned short us[64]; u32x4 q[8]; } pk;
#pragma unroll
    for (int c = 0; c < 64; c++) pk.us[c] = f16bits(xn[c * HW]);
    u32x4* dst = (u32x4*)(xt + ((size_t)n * HW + px) * 64);
#pragma unroll
    for (int i = 0; i < 8; i++) dst[i] = pk.q[i];
}

// ---------------------------------------------------------------------------
// Kernel 0: weight repack into MFMA fragment order (f16 bits).
//  wfrag (main): idx = (((k*4+nf)*2+kc)*64 + l)*8 + j
//  wauxf (aux, 32 out-ch padded from 27): idx = ((k*4 + ga*2 + kc)*64 + l)*8 + j
//  baux  f32[32]: b_off | b_mod | 0
// ---------------------------------------------------------------------------
__global__ __launch_bounds__(256) void prep_weights(
        const float* __restrict__ w, const float* __restrict__ w_off,
        const float* __restrict__ w_mod, const float* __restrict__ b_off,
        const float* __restrict__ b_mod, unsigned short* __restrict__ wfrag,
        unsigned short* __restrict__ wauxf, float* __restrict__ baux) {
    int idx = blockIdx.x * 256 + threadIdx.x;
    if (idx < 36864) {
        int j    = idx & 7;
        int lane = (idx >> 3) & 63;
        int kc   = (idx >> 9) & 1;
        int g    = (idx >> 10) & 3;
        int k    = idx >> 12;
        int o = g * 16 + (lane & 15);
        int c = kc * 32 + (lane >> 4) * 8 + j;
        wfrag[idx] = f16bits(w[(o * 64 + c) * 9 + k]);
    }
    if (idx < 18432) {
        int j    = idx & 7;
        int lane = (idx >> 3) & 63;
        int kc   = (idx >> 9) & 1;
        int ga   = (idx >> 10) & 1;
        int k    = idx >> 11;
        int o = ga * 16 + (lane & 15);
        int c = kc * 32 + (lane >> 4) * 8 + j;
        float v = 0.f;
        if (o < 18)      v = w_off[(o * 64 + c) * 9 + k];
        else if (o < 27) v = w_mod[((o - 18) * 64 + c) * 9 + k];
        wauxf[idx] = f16bits(v);
    }
    if (idx < 32) {
        float v = 0.f;
        if (idx < 18)      v = b_off[idx];
        else if (idx < 27) v = b_mod[idx - 18];
        baux[idx] = v;
    }
}

// ---------------------------------------------------------------------------
// Fused kernel. Tile = 2 output rows x 32 cols. 4 waves: wave = (r2<<1)|g2.
// Window: 6 rows x 36 cols, 128 B/slot, XOR-swizzled (byte ^ (slot&7)<<4).
// LDS: win 27648 + oml 4096 + planW 9216 + planC 9216 = 50176 B.
// ---------------------------------------------------------------------------
__global__ __launch_bounds__(256, 3) void dcn_fused(
        const unsigned short* __restrict__ xt,
        const unsigned short* __restrict__ wfrag,
        const unsigned short* __restrict__ wauxf,
        const float* __restrict__ baux,
        const float* __restrict__ bias,
        float* __restrict__ out) {
    __shared__ __align__(16) unsigned short win[216 * 64];  // 27648 B
    __shared__ __align__(16) unsigned short oml[2][32][32]; // 4096 B pixel-major
    __shared__ __align__(16) u32x4 planW[576];              // 9216 B (dup f16 wts)
    __shared__ __align__(16) i32x4 planC[576];              // 9216 B (corner codes)

    int tid = threadIdx.x;
    int l   = tid & 63;
    int wv  = __builtin_amdgcn_readfirstlane(tid >> 6);   // 0..3
    int r2  = wv >> 1;        // output row within tile
    int g2  = wv & 1;         // 16-px half within row

    int id = blockIdx.x;                        // 0..2303
    int sw = (id & 7) * 288 + (id >> 3);        // bijective XCD swizzle
    int n  = sw / 576;
    int r  = sw % 576;
    int ho2    = (r / 6) * 2;
    int wobase = (r % 6) * 32;

    const char* xb = (const char*)xt + (size_t)n * HW * 128;

    // ---------------- stage the 6x36 window into LDS (swizzled) ----------
    if (tid < 216) {
        int rw = tid / 36, cl = tid - rw * 36;
        int gy = iclamp(ho2 - 2 + rw, 0, HH - 1);
        int gx = iclamp(wobase - 2 + cl, 0, WW - 1);
        const u32x4* src = (const u32x4*)(xb + ((size_t)gy * WW + gx) * 128);
        char* dst = (char*)win + tid * 128;
        int xw = (tid & 7) << 4;
#pragma unroll
        for (int c = 0; c < 8; c++)
            *(u32x4*)(dst + ((c * 16) ^ xw)) = src[c];
    }
    __syncthreads();

    // ================= Phase A: aux conv for this tile =================
    {
        f32x4 aacc[2];
        aacc[0] = (f32x4){0.f, 0.f, 0.f, 0.f};
        aacc[1] = (f32x4){0.f, 0.f, 0.f, 0.f};
        const f16x8 zero8 = (f16x8){0, 0, 0, 0, 0, 0, 0, 0};
        int pa   = g2 * 16 + (l & 15);          // px in row, 0..31
        int cba  = (l >> 4) * 16;               // 8-ch chunk byte offset
        int ho_a = ho2 + r2;

#pragma unroll 1
        for (int k = 0; k < 9; k++) {
            int ky = k / 3, kx = k - 3 * (k / 3);
            int ys = ho_a + ky - 1;
            if ((unsigned)ys >= (unsigned)HH) continue;   // uniform row skip
            int xs = wobase + pa + kx - 1;
            bool ok = (unsigned)xs < (unsigned)WW;
            int sA = (ky + 1 + r2) * 36 + (pa + kx + 1);  // window slot
            const char* pp = (const char*)win + sA * 128;
            int xw = (sA & 7) << 4;
            const f16x8* wa = ((const f16x8*)wauxf) + (k * 4) * 64 + l;
#pragma unroll
            for (int kc = 0; kc < 2; kc++) {
                f16x8 bv = *(const f16x8*)(pp + ((kc * 64 + cba) ^ xw));
                if (!ok) bv = zero8;
                f16x8 a0 = wa[(kc)     * 64];      // o 0..15
                f16x8 a1 = wa[(2 + kc) * 64];      // o 16..31
                aacc[0] = __builtin_amdgcn_mfma_f32_16x16x32_f16(a0, bv, aacc[0], 0, 0, 0);
                aacc[1] = __builtin_amdgcn_mfma_f32_16x16x32_f16(a1, bv, aacc[1], 0, 0, 0);
            }
        }
#pragma unroll
        for (int h = 0; h < 2; h++) {
#pragma unroll
            for (int rr = 0; rr < 2; rr++) {      // write f16 pairs as u32
                int o = h * 16 + (l >> 4) * 4 + rr * 2;
                float v0 = aacc[h][rr * 2]     + baux[o];
                float v1 = aacc[h][rr * 2 + 1] + baux[o + 1];
                if (o     >= 18) v0 = 2.f / (1.f + expf(-v0));
                if (o + 1 >= 18) v1 = 2.f / (1.f + expf(-v1));
                unsigned int pk = (unsigned int)f16bits(v0)
                                | ((unsigned int)f16bits(v1) << 16);
                *(unsigned int*)&oml[r2][pa][o] = pk;
            }
        }
    }
    __syncthreads();

    // ====== Phase P: per (row,px,tap) sampling plan (576, once per block) ====
    for (int i = tid; i < 576; i += 256) {
        int rp = i / 9;                 // 0..63 = r2p*32 + px
        int k  = i - rp * 9;
        int r2p = rp >> 5, px = rp & 31;
        int ho_p  = ho2 + r2p;
        int wox_p = wobase + px;

        int ky = k / 3, kx = k - 3 * (k / 3);
        unsigned int oyx = *(const unsigned int*)&oml[r2p][px][2 * k];
        float offy = h2f((unsigned short)(oyx & 0xffffu));
        float offx = h2f((unsigned short)(oyx >> 16));
        float mm   = h2f(oml[r2p][px][18 + k]);
        float py  = offy + (float)(ho_p - 1 + ky);
        float pxf = offx + (float)(wox_p - 1 + kx);
        float y0f = floorf(py), x0f = floorf(pxf);
        float ly = py - y0f, lx = pxf - x0f;
        int y0 = (int)y0f, x0 = (int)x0f;
        int y1 = y0 + 1, x1 = x0 + 1;
        bool y0ok = (unsigned)y0 < (unsigned)HH, y1ok = (unsigned)y1 < (unsigned)HH;
        bool x0ok = (unsigned)x0 < (unsigned)WW, x1ok = (unsigned)x1 < (unsigned)WW;
        float wt0 = (y0ok && x0ok) ? mm * (1.f - ly) * (1.f - lx) : 0.f;
        float wt1 = (y0ok && x1ok) ? mm * (1.f - ly) * lx         : 0.f;
        float wt2 = (y1ok && x0ok) ? mm * ly * (1.f - lx)         : 0.f;
        float wt3 = (y1ok && x1ok) ? mm * ly * lx                 : 0.f;
        int y0c = iclamp(y0, 0, HH - 1), y1c = iclamp(y1, 0, HH - 1);
        int x0c = iclamp(x0, 0, WW - 1), x1c = iclamp(x1, 0, WW - 1);
        int sy0 = y0c - ho2 + 2,    sy1 = y1c - ho2 + 2;     // want 0..5
        int sx0 = x0c - wobase + 2, sx1 = x1c - wobase + 2;  // want 0..35
        int sy0c = iclamp(sy0, 0, 5),  sy1c = iclamp(sy1, 0, 5);
        int sx0c = iclamp(sx0, 0, 35), sx1c = iclamp(sx1, 0, 35);
        bool fb0 = (wt0 > 0.f) && ((sy0 != sy0c) | (sx0 != sx0c));
        bool fb1 = (wt1 > 0.f) && ((sy0 != sy0c) | (sx1 != sx1c));
        bool fb2 = (wt2 > 0.f) && ((sy1 != sy1c) | (sx0 != sx0c));
        bool fb3 = (wt3 > 0.f) && ((sy1 != sy1c) | (sx1 != sx1c));
        int c0 = fb0 ? -(y0c * WW + x0c) - 1 : sy0c * 36 + sx0c;
        int c1 = fb1 ? -(y0c * WW + x1c) - 1 : sy0c * 36 + sx1c;
        int c2 = fb2 ? -(y1c * WW + x0c) - 1 : sy1c * 36 + sx0c;
        int c3 = fb3 ? -(y1c * WW + x1c) - 1 : sy1c * 36 + sx1c;

        planW[i] = (u32x4){dup16(wt0), dup16(wt1), dup16(wt2), dup16(wt3)};
        planC[i] = (i32x4){c0, c1, c2, c3};
    }
    __syncthreads();   // window + plans ready; no further barriers

    // ================= Phase B: deform sample + main conv =================
    f32x4 acc[4];
#pragma unroll
    for (int nf = 0; nf < 4; nf++) acc[nf] = (f32x4){0.f, 0.f, 0.f, 0.f};

    int p_loc = l & 15;             // pixel within wave's 16 (M-row)
    int chunk = l >> 4;             // K-chunk 0..3
    int p     = g2 * 16 + p_loc;    // pixel in row, 0..31
    int ho_w  = ho2 + r2;
    int cb0   = chunk * 16;         // chunk byte offset within pixel line
    int cb1   = cb0 + 64;
    const char* planWp = (const char*)planW + (r2 * 32 + p) * 9 * 16;
    const char* planCp = (const char*)planC + (r2 * 32 + p) * 9 * 16;

    union Q { u32x4 u; __half2 h2[4]; };

#pragma unroll 1
    for (int k = 0; k < 9; k++) {
        // weight B-fragments (L1-broadcast across waves) — issue early
        const f16x8* wfk = ((const f16x8*)wfrag) + (k * 8) * 64 + l;
        f16x8 wB[8];
#pragma unroll
        for (int f = 0; f < 8; f++) wB[f] = wfk[f * 64];

        // --- plan reads (broadcast across the 4 chunk-lanes of a pixel) ---
        union { u32x4 u; __half2 h2[4]; } pw;
        pw.u = *(const u32x4*)(planWp + k * 16);
        i32x4 pc = *(const i32x4*)(planCp + k * 16);
        int c0 = pc.x, c1 = pc.y, c2 = pc.z, c3 = pc.w;

        // --- LDS corner addresses (cheap: slot*128, xor swizzle) ---
        int d0 = c0 < 0 ? 0 : c0, d1 = c1 < 0 ? 0 : c1;
        int d2 = c2 < 0 ? 0 : c2, d3 = c3 < 0 ? 0 : c3;
        const char* b0 = (const char*)win + d0 * 128;
        const char* b1 = (const char*)win + d1 * 128;
        const char* b2 = (const char*)win + d2 * 128;
        const char* b3 = (const char*)win + d3 * 128;
        int x0 = (d0 & 7) << 4, x1 = (d1 & 7) << 4;
        int x2 = (d2 & 7) << 4, x3 = (d3 & 7) << 4;
        Q q0, q1, q2, q3, q4, q5, q6, q7;
        q0.u = *(const u32x4*)(b0 + (cb0 ^ x0));
        q1.u = *(const u32x4*)(b0 + (cb1 ^ x0));
        q2.u = *(const u32x4*)(b1 + (cb0 ^ x1));
        q3.u = *(const u32x4*)(b1 + (cb1 ^ x1));
        q4.u = *(const u32x4*)(b2 + (cb0 ^ x2));
        q5.u = *(const u32x4*)(b2 + (cb1 ^ x2));
        q6.u = *(const u32x4*)(b3 + (cb0 ^ x3));
        q7.u = *(const u32x4*)(b3 + (cb1 ^ x3));

        // --- rare fallback: c<0 encodes -(global pixel)-1 ---
        if (__builtin_expect((c0 | c1 | c2 | c3) < 0, 0)) {
            if (c0 < 0) { const char* gp = xb + (size_t)(-c0 - 1) * 128 + cb0;
                          q0.u = *(const u32x4*)gp; q1.u = *(const u32x4*)(gp + 64); }
            if (c1 < 0) { const char* gp = xb + (size_t)(-c1 - 1) * 128 + cb0;
                          q2.u = *(const u32x4*)gp; q3.u = *(const u32x4*)(gp + 64); }
            if (c2 < 0) { const char* gp = xb + (size_t)(-c2 - 1) * 128 + cb0;
                          q4.u = *(const u32x4*)gp; q5.u = *(const u32x4*)(gp + 64); }
            if (c3 < 0) { const char* gp = xb + (size_t)(-c3 - 1) * 128 + cb0;
                          q6.u = *(const u32x4*)gp; q7.u = *(const u32x4*)(gp + 64); }
        }

        // --- packed f16 bilinear -> A-fragments (v_pk_fma_f16) ---
        union { __half2 h2[4]; f16x8 v; } fA0, fA1;
#pragma unroll
        for (int j = 0; j < 4; j++) {
            __half2 t = __hmul2(q0.h2[j], pw.h2[0]);
            t = __hfma2(q2.h2[j], pw.h2[1], t);
            t = __hfma2(q4.h2[j], pw.h2[2], t);
            t = __hfma2(q6.h2[j], pw.h2[3], t);
            fA0.h2[j] = t;
            __half2 s = __hmul2(q1.h2[j], pw.h2[0]);
            s = __hfma2(q3.h2[j], pw.h2[1], s);
            s = __hfma2(q5.h2[j], pw.h2[2], s);
            s = __hfma2(q7.h2[j], pw.h2[3], s);
            fA1.h2[j] = s;
        }

        // --- 8 MFMA: D[p][o] += V(16x32) * W^T(32x16) per o-tile ---
        __builtin_amdgcn_s_setprio(1);
#pragma unroll
        for (int nf = 0; nf < 4; nf++) {
            acc[nf] = __builtin_amdgcn_mfma_f32_16x16x32_f16(fA0.v, wB[nf * 2],     acc[nf], 0, 0, 0);
            acc[nf] = __builtin_amdgcn_mfma_f32_16x16x32_f16(fA1.v, wB[nf * 2 + 1], acc[nf], 0, 0, 0);
        }
        __builtin_amdgcn_s_setprio(0);
    }

    // epilogue: D map row=(l>>4)*4+rr = pixel-in-wave, col=l&15 = o-in-tile
    // out lines: full 128-B lines per block (r12 lesson).
#pragma unroll
    for (int nf = 0; nf < 4; nf++) {
        int o = nf * 16 + p_loc;
        float bo = bias[o];
        int wo = wobase + g2 * 16 + chunk * 4;
        float* op = out + (((size_t)n * COUT + o) * HH + ho_w) * WW + wo;
#pragma unroll
        for (int rr = 0; rr < 4; rr++) {
            float v = acc[nf][rr] + bo;
            op[rr] = fmaxf(v, 0.f);
        }
    }
}

// ---------------------------------------------------------------------------
extern "C" void kernel_launch(void* const* d_in, const int* in_sizes, int n_in,
                              void* d_out, int out_size, void* d_ws, size_t ws_size,
                              hipStream_t stream) {
    const float* x     = (const float*)d_in[0];
    const float* w_off = (const float*)d_in[1];
    const float* b_off = (const float*)d_in[2];
    const float* w_mod = (const float*)d_in[3];
    const float* b_mod = (const float*)d_in[4];
    const float* w     = (const float*)d_in[5];
    const float* b     = (const float*)d_in[6];
    float* out = (float*)d_out;

    // ws layout: wfrag f16[36864] | wauxf f16[18432] | baux f32[32] |
    //            xt f16 NHWC [4*HW*64]                       (~19 MB)
    unsigned short* wfrag = (unsigned short*)d_ws;
    unsigned short* wauxf = wfrag + 36864;
    float* baux = (float*)(wauxf + 18432);
    unsigned short* xt = (unsigned short*)(baux + 32);

    to_nhwc<<<dim3(144, NB), dim3(256), 0, stream>>>(x, xt);
    prep_weights<<<dim3(144), dim3(256), 0, stream>>>(w, w_off, w_mod, b_off,
                                                      b_mod, wfrag, wauxf, baux);
    dcn_fused<<<dim3(2304), dim3(256), 0, stream>>>(xt, wfrag, wauxf, baux, b, out);
}

// Round 16
// 71.470 us; speedup vs baseline: 1.0578x; 1.0134x over previous
//
#include <hip/hip_runtime.h>
#include <hip/hip_bf16.h>
#include <hip/hip_fp16.h>
#include <math.h>

// DCNv2 forward, fully fused, f16 pipeline with PACKED plan precompute:
//  stage 6x36 NHWC f16 window in LDS (XOR-swizzled) ->
//  Phase A: aux conv (f16 MFMA) -> oml (pixel-major f16) in LDS ->
//  Phase P: per (row,px,tap) ONE 16-B plan entry {w01,w23,c01,c23}:
//           4 f16 bilinear weights + 4 u16 window-slot codes (0xFFFF = rare
//           out-of-window corner, Phase B recomputes from oml) ->
//  Phase B: rolled 9-tap loop; per lane: 1 plan ds_read_b128, ~10 unpack ops,
//           8 corner ds_read_b128, packed-f16 bilinear straight into MFMA
//           A-fragments (D = V*W^T), 8 MFMA.
// LDS = 27648 + 4096 + 9216 = 40960 B exactly -> 4 blocks/CU (16 waves/CU).
// Tile = 2 rows x 32 cols, 4 waves. x [4,64,192,192] f32 -> out same shape.

#define NB   4
#define CIN  64
#define COUT 64
#define HH   192
#define WW   192
#define HW   (HH*WW)

typedef __attribute__((ext_vector_type(4))) float f32x4;
typedef __attribute__((ext_vector_type(8))) _Float16 f16x8;
typedef __attribute__((ext_vector_type(4))) unsigned int u32x4;

__device__ __forceinline__ int iclamp(int v, int lo, int hi) {
    return v < lo ? lo : (v > hi ? hi : v);
}
__device__ __forceinline__ unsigned short f16bits(float f) {
    __half h = __float2half(f);
    union { __half h; unsigned short u; } t; t.h = h; return t.u;
}
__device__ __forceinline__ float h2f(unsigned short u) {
    union { unsigned short u; __half h; } t; t.u = u; return __half2float(t.h);
}
__device__ __forceinline__ __half2 dup_lo(unsigned int u) {
    unsigned int lo = u & 0xffffu;
    unsigned int d = lo | (lo << 16);
    union { unsigned int u; __half2 h; } t; t.u = d; return t.h;
}
__device__ __forceinline__ __half2 dup_hi(unsigned int u) {
    unsigned int hi = u >> 16;
    unsigned int d = hi | (hi << 16);
    union { unsigned int u; __half2 h; } t; t.u = d; return t.h;
}

// ---------------------------------------------------------------------------
// Kernel A: x f32 NCHW -> xt f16 NHWC (128 B per pixel).
// ---------------------------------------------------------------------------
__global__ __launch_bounds__(256) void to_nhwc(
        const float* __restrict__ x, unsigned short* __restrict__ xt) {
    int n  = blockIdx.y;
    int px = blockIdx.x * 256 + threadIdx.x;     // 0..HW-1
    const float* xn = x + (size_t)n * CIN * HW + px;
    union { unsigned short us[64]; u32x4 q[8]; } pk;
#pragma unroll
    for (int c = 0; c < 64; c++) pk.us[c] = f16bits(xn[c * HW]);
    u32x4* dst = (u32x4*)(xt + ((size_t)n * HW + px) * 64);
#pragma unroll
    for (int i = 0; i < 8; i++) dst[i] = pk.q[i];
}

// ---------------------------------------------------------------------------
// Kernel 0: weight repack into MFMA fragment order (f16 bits).
//  wfrag (main): idx = (((k*4+nf)*2+kc)*64 + l)*8 + j
//  wauxf (aux, 32 out-ch padded from 27): idx = ((k*4 + ga*2 + kc)*64 + l)*8 + j
//  baux  f32[32]: b_off | b_mod | 0
// ---------------------------------------------------------------------------
__global__ __launch_bounds__(256) void prep_weights(
        const float* __restrict__ w, const float* __restrict__ w_off,
        const float* __restrict__ w_mod, const float* __restrict__ b_off,
        const float* __restrict__ b_mod, unsigned short* __restrict__ wfrag,
        unsigned short* __restrict__ wauxf, float* __restrict__ baux) {
    int idx = blockIdx.x * 256 + threadIdx.x;
    if (idx < 36864) {
        int j    = idx & 7;
        int lane = (idx >> 3) & 63;
        int kc   = (idx >> 9) & 1;
        int g    = (idx >> 10) & 3;
        int k    = idx >> 12;
        int o = g * 16 + (lane & 15);
        int c = kc * 32 + (lane >> 4) * 8 + j;
        wfrag[idx] = f16bits(w[(o * 64 + c) * 9 + k]);
    }
    if (idx < 18432) {
        int j    = idx & 7;
        int lane = (idx >> 3) & 63;
        int kc   = (idx >> 9) & 1;
        int ga   = (idx >> 10) & 1;
        int k    = idx >> 11;
        int o = ga * 16 + (lane & 15);
        int c = kc * 32 + (lane >> 4) * 8 + j;
        float v = 0.f;
        if (o < 18)      v = w_off[(o * 64 + c) * 9 + k];
        else if (o < 27) v = w_mod[((o - 18) * 64 + c) * 9 + k];
        wauxf[idx] = f16bits(v);
    }
    if (idx < 32) {
        float v = 0.f;
        if (idx < 18)      v = b_off[idx];
        else if (idx < 27) v = b_mod[idx - 18];
        baux[idx] = v;
    }
}

// ---------------------------------------------------------------------------
// Fused kernel. Tile = 2 output rows x 32 cols. 4 waves: wave = (r2<<1)|g2.
// Window: 6 rows x 36 cols, 128 B/slot, XOR-swizzled (byte ^ (slot&7)<<4).
// LDS: win 27648 + oml 4096 + plan 9216 = 40960 B (4 blocks/CU).
// ---------------------------------------------------------------------------
__global__ __launch_bounds__(256, 4) void dcn_fused(
        const unsigned short* __restrict__ xt,
        const unsigned short* __restrict__ wfrag,
        const unsigned short* __restrict__ wauxf,
        const float* __restrict__ baux,
        const float* __restrict__ bias,
        float* __restrict__ out) {
    __shared__ __align__(16) unsigned short win[216 * 64];  // 27648 B
    __shared__ __align__(16) unsigned short oml[2][32][32]; // 4096 B pixel-major
    __shared__ __align__(16) u32x4 plan[576];               // 9216 B packed

    int tid = threadIdx.x;
    int l   = tid & 63;
    int wv  = __builtin_amdgcn_readfirstlane(tid >> 6);   // 0..3
    int r2  = wv >> 1;        // output row within tile
    int g2  = wv & 1;         // 16-px half within row

    int id = blockIdx.x;                        // 0..2303
    int sw = (id & 7) * 288 + (id >> 3);        // bijective XCD swizzle
    int n  = sw / 576;
    int r  = sw % 576;
    int ho2    = (r / 6) * 2;
    int wobase = (r % 6) * 32;

    const char* xb = (const char*)xt + (size_t)n * HW * 128;

    // ---------------- stage the 6x36 window into LDS (swizzled) ----------
    if (tid < 216) {
        int rw = tid / 36, cl = tid - rw * 36;
        int gy = iclamp(ho2 - 2 + rw, 0, HH - 1);
        int gx = iclamp(wobase - 2 + cl, 0, WW - 1);
        const u32x4* src = (const u32x4*)(xb + ((size_t)gy * WW + gx) * 128);
        char* dst = (char*)win + tid * 128;
        int xw = (tid & 7) << 4;
#pragma unroll
        for (int c = 0; c < 8; c++)
            *(u32x4*)(dst + ((c * 16) ^ xw)) = src[c];
    }
    __syncthreads();

    // ================= Phase A: aux conv for this tile =================
    {
        f32x4 aacc[2];
        aacc[0] = (f32x4){0.f, 0.f, 0.f, 0.f};
        aacc[1] = (f32x4){0.f, 0.f, 0.f, 0.f};
        const f16x8 zero8 = (f16x8){0, 0, 0, 0, 0, 0, 0, 0};
        int pa   = g2 * 16 + (l & 15);          // px in row, 0..31
        int cba  = (l >> 4) * 16;               // 8-ch chunk byte offset
        int ho_a = ho2 + r2;

#pragma unroll 1
        for (int k = 0; k < 9; k++) {
            int ky = k / 3, kx = k - 3 * (k / 3);
            int ys = ho_a + ky - 1;
            if ((unsigned)ys >= (unsigned)HH) continue;   // uniform row skip
            int xs = wobase + pa + kx - 1;
            bool ok = (unsigned)xs < (unsigned)WW;
            int sA = (ky + 1 + r2) * 36 + (pa + kx + 1);  // window slot
            const char* pp = (const char*)win + sA * 128;
            int xw = (sA & 7) << 4;
            const f16x8* wa = ((const f16x8*)wauxf) + (k * 4) * 64 + l;
#pragma unroll
            for (int kc = 0; kc < 2; kc++) {
                f16x8 bv = *(const f16x8*)(pp + ((kc * 64 + cba) ^ xw));
                if (!ok) bv = zero8;
                f16x8 a0 = wa[(kc)     * 64];      // o 0..15
                f16x8 a1 = wa[(2 + kc) * 64];      // o 16..31
                aacc[0] = __builtin_amdgcn_mfma_f32_16x16x32_f16(a0, bv, aacc[0], 0, 0, 0);
                aacc[1] = __builtin_amdgcn_mfma_f32_16x16x32_f16(a1, bv, aacc[1], 0, 0, 0);
            }
        }
#pragma unroll
        for (int h = 0; h < 2; h++) {
#pragma unroll
            for (int rr = 0; rr < 2; rr++) {      // write f16 pairs as u32
                int o = h * 16 + (l >> 4) * 4 + rr * 2;
                float v0 = aacc[h][rr * 2]     + baux[o];
                float v1 = aacc[h][rr * 2 + 1] + baux[o + 1];
                if (o     >= 18) v0 = 2.f / (1.f + expf(-v0));
                if (o + 1 >= 18) v1 = 2.f / (1.f + expf(-v1));
                unsigned int pk = (unsigned int)f16bits(v0)
                                | ((unsigned int)f16bits(v1) << 16);
                *(unsigned int*)&oml[r2][pa][o] = pk;
            }
        }
    }
    __syncthreads();

    // ====== Phase P: packed sampling plan (576 entries, once per block) ====
    for (int i = tid; i < 576; i += 256) {
        int rp = i / 9;                 // 0..63 = r2p*32 + px
        int k  = i - rp * 9;
        int r2p = rp >> 5, px = rp & 31;
        int ho_p  = ho2 + r2p;
        int wox_p = wobase + px;

        int ky = k / 3, kx = k - 3 * (k / 3);
        unsigned int oyx = *(const unsigned int*)&oml[r2p][px][2 * k];
        float offy = h2f((unsigned short)(oyx & 0xffffu));
        float offx = h2f((unsigned short)(oyx >> 16));
        float mm   = h2f(oml[r2p][px][18 + k]);
        float py  = offy + (float)(ho_p - 1 + ky);
        float pxf = offx + (float)(wox_p - 1 + kx);
        float y0f = floorf(py), x0f = floorf(pxf);
        float ly = py - y0f, lx = pxf - x0f;
        int y0 = (int)y0f, x0 = (int)x0f;
        int y1 = y0 + 1, x1 = x0 + 1;
        bool y0ok = (unsigned)y0 < (unsigned)HH, y1ok = (unsigned)y1 < (unsigned)HH;
        bool x0ok = (unsigned)x0 < (unsigned)WW, x1ok = (unsigned)x1 < (unsigned)WW;
        float wt0 = (y0ok && x0ok) ? mm * (1.f - ly) * (1.f - lx) : 0.f;
        float wt1 = (y0ok && x1ok) ? mm * (1.f - ly) * lx         : 0.f;
        float wt2 = (y1ok && x0ok) ? mm * ly * (1.f - lx)         : 0.f;
        float wt3 = (y1ok && x1ok) ? mm * ly * lx                 : 0.f;
        int y0c = iclamp(y0, 0, HH - 1), y1c = iclamp(y1, 0, HH - 1);
        int x0c = iclamp(x0, 0, WW - 1), x1c = iclamp(x1, 0, WW - 1);
        int sy0 = y0c - ho2 + 2,    sy1 = y1c - ho2 + 2;     // want 0..5
        int sx0 = x0c - wobase + 2, sx1 = x1c - wobase + 2;  // want 0..35
        int sy0c = iclamp(sy0, 0, 5),  sy1c = iclamp(sy1, 0, 5);
        int sx0c = iclamp(sx0, 0, 35), sx1c = iclamp(sx1, 0, 35);
        bool fb0 = (wt0 > 0.f) && ((sy0 != sy0c) | (sx0 != sx0c));
        bool fb1 = (wt1 > 0.f) && ((sy0 != sy0c) | (sx1 != sx1c));
        bool fb2 = (wt2 > 0.f) && ((sy1 != sy1c) | (sx0 != sx0c));
        bool fb3 = (wt3 > 0.f) && ((sy1 != sy1c) | (sx1 != sx1c));
        unsigned int c0 = fb0 ? 0xffffu : (unsigned int)(sy0c * 36 + sx0c);
        unsigned int c1 = fb1 ? 0xffffu : (unsigned int)(sy0c * 36 + sx1c);
        unsigned int c2 = fb2 ? 0xffffu : (unsigned int)(sy1c * 36 + sx0c);
        unsigned int c3 = fb3 ? 0xffffu : (unsigned int)(sy1c * 36 + sx1c);

        unsigned int w01 = (unsigned int)f16bits(wt0) | ((unsigned int)f16bits(wt1) << 16);
        unsigned int w23 = (unsigned int)f16bits(wt2) | ((unsigned int)f16bits(wt3) << 16);
        plan[i] = (u32x4){w01, w23, c0 | (c1 << 16), c2 | (c3 << 16)};
    }
    __syncthreads();   // window + oml + plans ready; no further barriers

    // ================= Phase B: deform sample + main conv =================
    f32x4 acc[4];
#pragma unroll
    for (int nf = 0; nf < 4; nf++) acc[nf] = (f32x4){0.f, 0.f, 0.f, 0.f};

    int p_loc = l & 15;             // pixel within wave's 16 (M-row)
    int chunk = l >> 4;             // K-chunk 0..3
    int p     = g2 * 16 + p_loc;    // pixel in row, 0..31
    int ho_w  = ho2 + r2;
    int wox   = wobase + p;         // global wo of this pixel
    int cb0   = chunk * 16;         // chunk byte offset within pixel line
    int cb1   = cb0 + 64;
    const u32x4* plp = plan + (r2 * 32 + p) * 9;
    const unsigned short* omp = &oml[r2][p][0];

    union Q { u32x4 u; __half2 h2[4]; };

#pragma unroll 1
    for (int k = 0; k < 9; k++) {
        // weight B-fragments (L1-broadcast across waves) — issue early
        const f16x8* wfk = ((const f16x8*)wfrag) + (k * 8) * 64 + l;
        f16x8 wB[8];
#pragma unroll
        for (int f = 0; f < 8; f++) wB[f] = wfk[f * 64];

        // --- one packed plan read (broadcast across 4 chunk-lanes) ---
        u32x4 pl = plp[k];
        unsigned int c0 = pl.z & 0xffffu, c1 = pl.z >> 16;
        unsigned int c2 = pl.w & 0xffffu, c3 = pl.w >> 16;

        // --- LDS corner addresses (clamped in-bounds for fb codes) ---
        int d0 = (int)(c0 & 255u), d1 = (int)(c1 & 255u);
        int d2 = (int)(c2 & 255u), d3 = (int)(c3 & 255u);
        const char* b0 = (const char*)win + d0 * 128;
        const char* b1 = (const char*)win + d1 * 128;
        const char* b2 = (const char*)win + d2 * 128;
        const char* b3 = (const char*)win + d3 * 128;
        int x0 = (d0 & 7) << 4, x1 = (d1 & 7) << 4;
        int x2 = (d2 & 7) << 4, x3 = (d3 & 7) << 4;
        Q q0, q1, q2, q3, q4, q5, q6, q7;
        q0.u = *(const u32x4*)(b0 + (cb0 ^ x0));
        q1.u = *(const u32x4*)(b0 + (cb1 ^ x0));
        q2.u = *(const u32x4*)(b1 + (cb0 ^ x1));
        q3.u = *(const u32x4*)(b1 + (cb1 ^ x1));
        q4.u = *(const u32x4*)(b2 + (cb0 ^ x2));
        q5.u = *(const u32x4*)(b2 + (cb1 ^ x2));
        q6.u = *(const u32x4*)(b3 + (cb0 ^ x3));
        q7.u = *(const u32x4*)(b3 + (cb1 ^ x3));

        // --- rare fallback: code 0xFFFF -> recompute global addr from oml ---
        if (__builtin_expect((c0 == 0xffffu) | (c1 == 0xffffu) |
                             (c2 == 0xffffu) | (c3 == 0xffffu), 0)) {
            int ky = k / 3, kx = k - 3 * (k / 3);
            unsigned int oyx = *(const unsigned int*)(omp + 2 * k);
            float offy = h2f((unsigned short)(oyx & 0xffffu));
            float offx = h2f((unsigned short)(oyx >> 16));
            float py  = offy + (float)(ho_w - 1 + ky);
            float pxf = offx + (float)(wox - 1 + kx);
            int y0 = (int)floorf(py), x0i = (int)floorf(pxf);
            int y0c = iclamp(y0, 0, HH - 1),     y1c = iclamp(y0 + 1, 0, HH - 1);
            int x0c = iclamp(x0i, 0, WW - 1),    x1c = iclamp(x0i + 1, 0, WW - 1);
            if (c0 == 0xffffu) { const char* gp = xb + ((size_t)y0c * WW + x0c) * 128 + cb0;
                                 q0.u = *(const u32x4*)gp; q1.u = *(const u32x4*)(gp + 64); }
            if (c1 == 0xffffu) { const char* gp = xb + ((size_t)y0c * WW + x1c) * 128 + cb0;
                                 q2.u = *(const u32x4*)gp; q3.u = *(const u32x4*)(gp + 64); }
            if (c2 == 0xffffu) { const char* gp = xb + ((size_t)y1c * WW + x0c) * 128 + cb0;
                                 q4.u = *(const u32x4*)gp; q5.u = *(const u32x4*)(gp + 64); }
            if (c3 == 0xffffu) { const char* gp = xb + ((size_t)y1c * WW + x1c) * 128 + cb0;
                                 q6.u = *(const u32x4*)gp; q7.u = *(const u32x4*)(gp + 64); }
        }

        // --- packed f16 bilinear -> A-fragments (v_pk_fma_f16) ---
        __half2 wv0 = dup_lo(pl.x), wv1 = dup_hi(pl.x);
        __half2 wv2 = dup_lo(pl.y), wv3 = dup_hi(pl.y);
        union { __half2 h2[4]; f16x8 v; } fA0, fA1;
#pragma unroll
        for (int j = 0; j < 4; j++) {
            __half2 t = __hmul2(q0.h2[j], wv0);
            t = __hfma2(q2.h2[j], wv1, t);
            t = __hfma2(q4.h2[j], wv2, t);
            t = __hfma2(q6.h2[j], wv3, t);
            fA0.h2[j] = t;
            __half2 s = __hmul2(q1.h2[j], wv0);
            s = __hfma2(q3.h2[j], wv1, s);
            s = __hfma2(q5.h2[j], wv2, s);
            s = __hfma2(q7.h2[j], wv3, s);
            fA1.h2[j] = s;
        }

        // --- 8 MFMA: D[p][o] += V(16x32) * W^T(32x16) per o-tile ---
        __builtin_amdgcn_s_setprio(1);
#pragma unroll
        for (int nf = 0; nf < 4; nf++) {
            acc[nf] = __builtin_amdgcn_mfma_f32_16x16x32_f16(fA0.v, wB[nf * 2],     acc[nf], 0, 0, 0);
            acc[nf] = __builtin_amdgcn_mfma_f32_16x16x32_f16(fA1.v, wB[nf * 2 + 1], acc[nf], 0, 0, 0);
        }
        __builtin_amdgcn_s_setprio(0);
    }

    // epilogue: D map row=(l>>4)*4+rr = pixel-in-wave, col=l&15 = o-in-tile
    // out lines: full 128-B lines per block (r12 lesson).
#pragma unroll
    for (int nf = 0; nf < 4; nf++) {
        int o = nf * 16 + p_loc;
        float bo = bias[o];
        int wo = wobase + g2 * 16 + chunk * 4;
        float* op = out + (((size_t)n * COUT + o) * HH + ho_w) * WW + wo;
#pragma unroll
        for (int rr = 0; rr < 4; rr++) {
            float v = acc[nf][rr] + bo;
            op[rr] = fmaxf(v, 0.f);
        }
    }
}

// ---------------------------------------------------------------------------
extern "C" void kernel_launch(void* const* d_in, const int* in_sizes, int n_in,
                              void* d_out, int out_size, void* d_ws, size_t ws_size,
                              hipStream_t stream) {
    const float* x     = (const float*)d_in[0];
    const float* w_off = (const float*)d_in[1];
    const float* b_off = (const float*)d_in[2];
    const float* w_mod = (const float*)d_in[3];
    const float* b_mod = (const float*)d_in[4];
    const float* w     = (const float*)d_in[5];
    const float* b     = (const float*)d_in[6];
    float* out = (float*)d_out;

    // ws layout: wfrag f16[36864] | wauxf f16[18432] | baux f32[32] |
    //            xt f16 NHWC [4*HW*64]                       (~19 MB)
    unsigned short* wfrag = (unsigned short*)d_ws;
    unsigned short* wauxf = wfrag + 36864;
    float* baux = (float*)(wauxf + 18432);
    unsigned short* xt = (unsigned short*)(baux + 32);

    to_nhwc<<<dim3(144, NB), dim3(256), 0, stream>>>(x, xt);
    prep_weights<<<dim3(144), dim3(256), 0, stream>>>(w, w_off, w_mod, b_off,
                                                      b_mod, wfrag, wauxf, baux);
    dcn_fused<<<dim3(2304), dim3(256), 0, stream>>>(xt, wfrag, wauxf, baux, b, out);
}

// Round 17
// 62.306 us; speedup vs baseline: 1.2134x; 1.1471x over previous
//
#include <hip/hip_runtime.h>
#include <hip/hip_bf16.h>
#include <hip/hip_fp16.h>
#include <math.h>

// DCNv2 forward, fully fused (r17): NO separate layout pass — each block
// stages its 6x36 window STRAIGHT from f32 NCHW x into f16 LDS (XOR-swizzled,
// pixel-major), then:
//  Phase A: aux conv (f16 MFMA) -> oml (pixel-major f16) in LDS ->
//  Phase P: per (row,px,tap) ONE 16-B packed plan {w01,w23,c01,c23} ->
//  Phase B: rolled 9-tap loop; 1 plan ds_read_b128, 8 corner ds_read_b128,
//           packed-f16 bilinear straight into MFMA A-fragments (D = V*W^T),
//           8 MFMA. Rare out-of-window corners (code 0xFFFF) re-gather from
//           NCHW global under exec mask.
// LDS = 27648 + 4096 + 9216 = 40960 B -> 4 blocks/CU. Tile = 2 rows x 32 cols.
// x [4,64,192,192] f32; w_off [18,64,3,3]; b_off[18]; w_mod [9,64,3,3];
// b_mod[9]; w [64,64,3,3]; b[64]; out [4,64,192,192] f32.

#define NB   4
#define CIN  64
#define COUT 64
#define HH   192
#define WW   192
#define HW   (HH*WW)

typedef __attribute__((ext_vector_type(4))) float f32x4;
typedef __attribute__((ext_vector_type(8))) _Float16 f16x8;
typedef __attribute__((ext_vector_type(4))) unsigned int u32x4;

__device__ __forceinline__ int iclamp(int v, int lo, int hi) {
    return v < lo ? lo : (v > hi ? hi : v);
}
__device__ __forceinline__ unsigned short f16bits(float f) {
    __half h = __float2half(f);
    union { __half h; unsigned short u; } t; t.h = h; return t.u;
}
__device__ __forceinline__ float h2f(unsigned short u) {
    union { unsigned short u; __half h; } t; t.u = u; return __half2float(t.h);
}
__device__ __forceinline__ __half2 dup_lo(unsigned int u) {
    unsigned int lo = u & 0xffffu;
    unsigned int d = lo | (lo << 16);
    union { unsigned int u; __half2 h; } t; t.u = d; return t.h;
}
__device__ __forceinline__ __half2 dup_hi(unsigned int u) {
    unsigned int hi = u >> 16;
    unsigned int d = hi | (hi << 16);
    union { unsigned int u; __half2 h; } t; t.u = d; return t.h;
}

// ---------------------------------------------------------------------------
// Kernel 0: weight repack into MFMA fragment order (f16 bits).
//  wfrag (main): idx = (((k*4+nf)*2+kc)*64 + l)*8 + j
//  wauxf (aux, 32 out-ch padded from 27): idx = ((k*4 + ga*2 + kc)*64 + l)*8 + j
//  baux  f32[32]: b_off | b_mod | 0
// ---------------------------------------------------------------------------
__global__ __launch_bounds__(256) void prep_weights(
        const float* __restrict__ w, const float* __restrict__ w_off,
        const float* __restrict__ w_mod, const float* __restrict__ b_off,
        const float* __restrict__ b_mod, unsigned short* __restrict__ wfrag,
        unsigned short* __restrict__ wauxf, float* __restrict__ baux) {
    int idx = blockIdx.x * 256 + threadIdx.x;
    if (idx < 36864) {
        int j    = idx & 7;
        int lane = (idx >> 3) & 63;
        int kc   = (idx >> 9) & 1;
        int g    = (idx >> 10) & 3;
        int k    = idx >> 12;
        int o = g * 16 + (lane & 15);
        int c = kc * 32 + (lane >> 4) * 8 + j;
        wfrag[idx] = f16bits(w[(o * 64 + c) * 9 + k]);
    }
    if (idx < 18432) {
        int j    = idx & 7;
        int lane = (idx >> 3) & 63;
        int kc   = (idx >> 9) & 1;
        int ga   = (idx >> 10) & 1;
        int k    = idx >> 11;
        int o = ga * 16 + (lane & 15);
        int c = kc * 32 + (lane >> 4) * 8 + j;
        float v = 0.f;
        if (o < 18)      v = w_off[(o * 64 + c) * 9 + k];
        else if (o < 27) v = w_mod[((o - 18) * 64 + c) * 9 + k];
        wauxf[idx] = f16bits(v);
    }
    if (idx < 32) {
        float v = 0.f;
        if (idx < 18)      v = b_off[idx];
        else if (idx < 27) v = b_mod[idx - 18];
        baux[idx] = v;
    }
}

// ---------------------------------------------------------------------------
// Fused kernel. Tile = 2 output rows x 32 cols. 4 waves: wave = (r2<<1)|g2.
// Window: 6 rows x 36 cols, 128 B/slot, XOR-swizzled (byte ^ (slot&7)<<4),
// staged DIRECTLY from f32 NCHW x (coalesced 4B loads, f16 pack in-kernel).
// LDS: win 27648 + oml 4096 + plan 9216 = 40960 B (4 blocks/CU).
// ---------------------------------------------------------------------------
__global__ __launch_bounds__(256, 4) void dcn_fused(
        const float* __restrict__ x,
        const unsigned short* __restrict__ wfrag,
        const unsigned short* __restrict__ wauxf,
        const float* __restrict__ baux,
        const float* __restrict__ bias,
        float* __restrict__ out) {
    __shared__ __align__(16) unsigned short win[216 * 64];  // 27648 B
    __shared__ __align__(16) unsigned short oml[2][32][32]; // 4096 B pixel-major
    __shared__ __align__(16) u32x4 plan[576];               // 9216 B packed

    int tid = threadIdx.x;
    int l   = tid & 63;
    int wv  = __builtin_amdgcn_readfirstlane(tid >> 6);   // 0..3
    int r2  = wv >> 1;        // output row within tile
    int g2  = wv & 1;         // 16-px half within row

    int id = blockIdx.x;                        // 0..2303
    int sw = (id & 7) * 288 + (id >> 3);        // bijective XCD swizzle
    int n  = sw / 576;
    int r  = sw % 576;
    int ho2    = (r / 6) * 2;
    int wobase = (r % 6) * 32;

    const float* xn = x + (size_t)n * CIN * HW;

    // ------- stage the 6x36 window from f32 NCHW (coalesced, swizzled) -----
    if (tid < 216) {
        int rw = tid / 36, cl = tid - rw * 36;
        int gy = iclamp(ho2 - 2 + rw, 0, HH - 1);
        int gx = iclamp(wobase - 2 + cl, 0, WW - 1);
        const float* xp = xn + gy * WW + gx;    // lane-adjacent -> coalesced
        char* dst = (char*)win + tid * 128;
        int xw = (tid & 7) << 4;
#pragma unroll
        for (int c8 = 0; c8 < 8; c8++) {
            union { unsigned short us[8]; u32x4 q; } pk8;
#pragma unroll
            for (int j = 0; j < 8; j++)
                pk8.us[j] = f16bits(xp[(c8 * 8 + j) * HW]);
            *(u32x4*)(dst + ((c8 * 16) ^ xw)) = pk8.q;
        }
    }
    __syncthreads();

    // ================= Phase A: aux conv for this tile =================
    {
        f32x4 aacc[2];
        aacc[0] = (f32x4){0.f, 0.f, 0.f, 0.f};
        aacc[1] = (f32x4){0.f, 0.f, 0.f, 0.f};
        const f16x8 zero8 = (f16x8){0, 0, 0, 0, 0, 0, 0, 0};
        int pa   = g2 * 16 + (l & 15);          // px in row, 0..31
        int cba  = (l >> 4) * 16;               // 8-ch chunk byte offset
        int ho_a = ho2 + r2;

#pragma unroll 1
        for (int k = 0; k < 9; k++) {
            int ky = k / 3, kx = k - 3 * (k / 3);
            int ys = ho_a + ky - 1;
            if ((unsigned)ys >= (unsigned)HH) continue;   // uniform row skip
            int xs = wobase + pa + kx - 1;
            bool ok = (unsigned)xs < (unsigned)WW;
            int sA = (ky + 1 + r2) * 36 + (pa + kx + 1);  // window slot
            const char* pp = (const char*)win + sA * 128;
            int xw = (sA & 7) << 4;
            const f16x8* wa = ((const f16x8*)wauxf) + (k * 4) * 64 + l;
#pragma unroll
            for (int kc = 0; kc < 2; kc++) {
                f16x8 bv = *(const f16x8*)(pp + ((kc * 64 + cba) ^ xw));
                if (!ok) bv = zero8;
                f16x8 a0 = wa[(kc)     * 64];      // o 0..15
                f16x8 a1 = wa[(2 + kc) * 64];      // o 16..31
                aacc[0] = __builtin_amdgcn_mfma_f32_16x16x32_f16(a0, bv, aacc[0], 0, 0, 0);
                aacc[1] = __builtin_amdgcn_mfma_f32_16x16x32_f16(a1, bv, aacc[1], 0, 0, 0);
            }
        }
#pragma unroll
        for (int h = 0; h < 2; h++) {
#pragma unroll
            for (int rr = 0; rr < 2; rr++) {      // write f16 pairs as u32
                int o = h * 16 + (l >> 4) * 4 + rr * 2;
                float v0 = aacc[h][rr * 2]     + baux[o];
                float v1 = aacc[h][rr * 2 + 1] + baux[o + 1];
                if (o     >= 18) v0 = 2.f / (1.f + expf(-v0));
                if (o + 1 >= 18) v1 = 2.f / (1.f + expf(-v1));
                unsigned int pk = (unsigned int)f16bits(v0)
                                | ((unsigned int)f16bits(v1) << 16);
                *(unsigned int*)&oml[r2][pa][o] = pk;
            }
        }
    }
    __syncthreads();

    // ====== Phase P: packed sampling plan (576 entries, once per block) ====
    for (int i = tid; i < 576; i += 256) {
        int rp = i / 9;                 // 0..63 = r2p*32 + px
        int k  = i - rp * 9;
        int r2p = rp >> 5, px = rp & 31;
        int ho_p  = ho2 + r2p;
        int wox_p = wobase + px;

        int ky = k / 3, kx = k - 3 * (k / 3);
        unsigned int oyx = *(const unsigned int*)&oml[r2p][px][2 * k];
        float offy = h2f((unsigned short)(oyx & 0xffffu));
        float offx = h2f((unsigned short)(oyx >> 16));
        float mm   = h2f(oml[r2p][px][18 + k]);
        float py  = offy + (float)(ho_p - 1 + ky);
        float pxf = offx + (float)(wox_p - 1 + kx);
        float y0f = floorf(py), x0f = floorf(pxf);
        float ly = py - y0f, lx = pxf - x0f;
        int y0 = (int)y0f, x0 = (int)x0f;
        int y1 = y0 + 1, x1 = x0 + 1;
        bool y0ok = (unsigned)y0 < (unsigned)HH, y1ok = (unsigned)y1 < (unsigned)HH;
        bool x0ok = (unsigned)x0 < (unsigned)WW, x1ok = (unsigned)x1 < (unsigned)WW;
        float wt0 = (y0ok && x0ok) ? mm * (1.f - ly) * (1.f - lx) : 0.f;
        float wt1 = (y0ok && x1ok) ? mm * (1.f - ly) * lx         : 0.f;
        float wt2 = (y1ok && x0ok) ? mm * ly * (1.f - lx)         : 0.f;
        float wt3 = (y1ok && x1ok) ? mm * ly * lx                 : 0.f;
        int y0c = iclamp(y0, 0, HH - 1), y1c = iclamp(y1, 0, HH - 1);
        int x0c = iclamp(x0, 0, WW - 1), x1c = iclamp(x1, 0, WW - 1);
        int sy0 = y0c - ho2 + 2,    sy1 = y1c - ho2 + 2;     // want 0..5
        int sx0 = x0c - wobase + 2, sx1 = x1c - wobase + 2;  // want 0..35
        int sy0c = iclamp(sy0, 0, 5),  sy1c = iclamp(sy1, 0, 5);
        int sx0c = iclamp(sx0, 0, 35), sx1c = iclamp(sx1, 0, 35);
        bool fb0 = (wt0 > 0.f) && ((sy0 != sy0c) | (sx0 != sx0c));
        bool fb1 = (wt1 > 0.f) && ((sy0 != sy0c) | (sx1 != sx1c));
        bool fb2 = (wt2 > 0.f) && ((sy1 != sy1c) | (sx0 != sx0c));
        bool fb3 = (wt3 > 0.f) && ((sy1 != sy1c) | (sx1 != sx1c));
        unsigned int c0 = fb0 ? 0xffffu : (unsigned int)(sy0c * 36 + sx0c);
        unsigned int c1 = fb1 ? 0xffffu : (unsigned int)(sy0c * 36 + sx1c);
        unsigned int c2 = fb2 ? 0xffffu : (unsigned int)(sy1c * 36 + sx0c);
        unsigned int c3 = fb3 ? 0xffffu : (unsigned int)(sy1c * 36 + sx1c);

        unsigned int w01 = (unsigned int)f16bits(wt0) | ((unsigned int)f16bits(wt1) << 16);
        unsigned int w23 = (unsigned int)f16bits(wt2) | ((unsigned int)f16bits(wt3) << 16);
        plan[i] = (u32x4){w01, w23, c0 | (c1 << 16), c2 | (c3 << 16)};
    }
    __syncthreads();   // window + oml + plans ready; no further barriers

    // ================= Phase B: deform sample + main conv =================
    f32x4 acc[4];
#pragma unroll
    for (int nf = 0; nf < 4; nf++) acc[nf] = (f32x4){0.f, 0.f, 0.f, 0.f};

    int p_loc = l & 15;             // pixel within wave's 16 (M-row)
    int chunk = l >> 4;             // K-chunk 0..3
    int p     = g2 * 16 + p_loc;    // pixel in row, 0..31
    int ho_w  = ho2 + r2;
    int wox   = wobase + p;         // global wo of this pixel
    int cb0   = chunk * 16;         // chunk byte offset within pixel line
    int cb1   = cb0 + 64;
    int chb   = chunk * 8;          // first channel of cb0 chunk
    const u32x4* plp = plan + (r2 * 32 + p) * 9;
    const unsigned short* omp = &oml[r2][p][0];

    union Q { u32x4 u; __half2 h2[4]; unsigned short us[8]; };

#pragma unroll 1
    for (int k = 0; k < 9; k++) {
        // weight B-fragments (L1-broadcast across waves) — issue early
        const f16x8* wfk = ((const f16x8*)wfrag) + (k * 8) * 64 + l;
        f16x8 wB[8];
#pragma unroll
        for (int f = 0; f < 8; f++) wB[f] = wfk[f * 64];

        // --- one packed plan read (broadcast across 4 chunk-lanes) ---
        u32x4 pl = plp[k];
        unsigned int c0 = pl.z & 0xffffu, c1 = pl.z >> 16;
        unsigned int c2 = pl.w & 0xffffu, c3 = pl.w >> 16;

        // --- LDS corner addresses (clamped in-bounds for fb codes) ---
        int d0 = (int)(c0 & 255u), d1 = (int)(c1 & 255u);
        int d2 = (int)(c2 & 255u), d3 = (int)(c3 & 255u);
        const char* b0 = (const char*)win + d0 * 128;
        const char* b1 = (const char*)win + d1 * 128;
        const char* b2 = (const char*)win + d2 * 128;
        const char* b3 = (const char*)win + d3 * 128;
        int x0 = (d0 & 7) << 4, x1 = (d1 & 7) << 4;
        int x2 = (d2 & 7) << 4, x3 = (d3 & 7) << 4;
        Q q0, q1, q2, q3, q4, q5, q6, q7;
        q0.u = *(const u32x4*)(b0 + (cb0 ^ x0));
        q1.u = *(const u32x4*)(b0 + (cb1 ^ x0));
        q2.u = *(const u32x4*)(b1 + (cb0 ^ x1));
        q3.u = *(const u32x4*)(b1 + (cb1 ^ x1));
        q4.u = *(const u32x4*)(b2 + (cb0 ^ x2));
        q5.u = *(const u32x4*)(b2 + (cb1 ^ x2));
        q6.u = *(const u32x4*)(b3 + (cb0 ^ x3));
        q7.u = *(const u32x4*)(b3 + (cb1 ^ x3));

        // --- rare fallback: code 0xFFFF -> re-gather from f32 NCHW x ---
        if (__builtin_expect((c0 == 0xffffu) | (c1 == 0xffffu) |
                             (c2 == 0xffffu) | (c3 == 0xffffu), 0)) {
            int ky = k / 3, kx = k - 3 * (k / 3);
            unsigned int oyx = *(const unsigned int*)(omp + 2 * k);
            float offy = h2f((unsigned short)(oyx & 0xffffu));
            float offx = h2f((unsigned short)(oyx >> 16));
            float py  = offy + (float)(ho_w - 1 + ky);
            float pxf = offx + (float)(wox - 1 + kx);
            int y0 = (int)floorf(py), x0i = (int)floorf(pxf);
            int y0c = iclamp(y0, 0, HH - 1),  y1c = iclamp(y0 + 1, 0, HH - 1);
            int x0c = iclamp(x0i, 0, WW - 1), x1c = iclamp(x0i + 1, 0, WW - 1);
            if (c0 == 0xffffu) {
                const float* gp = xn + y0c * WW + x0c;
#pragma unroll
                for (int j = 0; j < 8; j++) {
                    q0.us[j] = f16bits(gp[(chb + j) * HW]);
                    q1.us[j] = f16bits(gp[(chb + 32 + j) * HW]);
                }
            }
            if (c1 == 0xffffu) {
                const float* gp = xn + y0c * WW + x1c;
#pragma unroll
                for (int j = 0; j < 8; j++) {
                    q2.us[j] = f16bits(gp[(chb + j) * HW]);
                    q3.us[j] = f16bits(gp[(chb + 32 + j) * HW]);
                }
            }
            if (c2 == 0xffffu) {
                const float* gp = xn + y1c * WW + x0c;
#pragma unroll
                for (int j = 0; j < 8; j++) {
                    q4.us[j] = f16bits(gp[(chb + j) * HW]);
                    q5.us[j] = f16bits(gp[(chb + 32 + j) * HW]);
                }
            }
            if (c3 == 0xffffu) {
                const float* gp = xn + y1c * WW + x1c;
#pragma unroll
                for (int j = 0; j < 8; j++) {
                    q6.us[j] = f16bits(gp[(chb + j) * HW]);
                    q7.us[j] = f16bits(gp[(chb + 32 + j) * HW]);
                }
            }
        }

        // --- packed f16 bilinear -> A-fragments (v_pk_fma_f16) ---
        __half2 wv0 = dup_lo(pl.x), wv1 = dup_hi(pl.x);
        __half2 wv2 = dup_lo(pl.y), wv3 = dup_hi(pl.y);
        union { __half2 h2[4]; f16x8 v; } fA0, fA1;
#pragma unroll
        for (int j = 0; j < 4; j++) {
            __half2 t = __hmul2(q0.h2[j], wv0);
            t = __hfma2(q2.h2[j], wv1, t);
            t = __hfma2(q4.h2[j], wv2, t);
            t = __hfma2(q6.h2[j], wv3, t);
            fA0.h2[j] = t;
            __half2 s = __hmul2(q1.h2[j], wv0);
            s = __hfma2(q3.h2[j], wv1, s);
            s = __hfma2(q5.h2[j], wv2, s);
            s = __hfma2(q7.h2[j], wv3, s);
            fA1.h2[j] = s;
        }

        // --- 8 MFMA: D[p][o] += V(16x32) * W^T(32x16) per o-tile ---
        __builtin_amdgcn_s_setprio(1);
#pragma unroll
        for (int nf = 0; nf < 4; nf++) {
            acc[nf] = __builtin_amdgcn_mfma_f32_16x16x32_f16(fA0.v, wB[nf * 2],     acc[nf], 0, 0, 0);
            acc[nf] = __builtin_amdgcn_mfma_f32_16x16x32_f16(fA1.v, wB[nf * 2 + 1], acc[nf], 0, 0, 0);
        }
        __builtin_amdgcn_s_setprio(0);
    }

    // epilogue: D map row=(l>>4)*4+rr = pixel-in-wave, col=l&15 = o-in-tile
    // out lines: full 128-B lines per block (r12 lesson).
#pragma unroll
    for (int nf = 0; nf < 4; nf++) {
        int o = nf * 16 + p_loc;
        float bo = bias[o];
        int wo = wobase + g2 * 16 + chunk * 4;
        float* op = out + (((size_t)n * COUT + o) * HH + ho_w) * WW + wo;
#pragma unroll
        for (int rr = 0; rr < 4; rr++) {
            float v = acc[nf][rr] + bo;
            op[rr] = fmaxf(v, 0.f);
        }
    }
}

// ---------------------------------------------------------------------------
extern "C" void kernel_launch(void* const* d_in, const int* in_sizes, int n_in,
                              void* d_out, int out_size, void* d_ws, size_t ws_size,
                              hipStream_t stream) {
    const float* x     = (const float*)d_in[0];
    const float* w_off = (const float*)d_in[1];
    const float* b_off = (const float*)d_in[2];
    const float* w_mod = (const float*)d_in[3];
    const float* b_mod = (const float*)d_in[4];
    const float* w     = (const float*)d_in[5];
    const float* b     = (const float*)d_in[6];
    float* out = (float*)d_out;

    // ws layout: wfrag f16[36864] | wauxf f16[18432] | baux f32[32]  (~111 KB)
    unsigned short* wfrag = (unsigned short*)d_ws;
    unsigned short* wauxf = wfrag + 36864;
    float* baux = (float*)(wauxf + 18432);

    prep_weights<<<dim3(144), dim3(256), 0, stream>>>(w, w_off, w_mod, b_off,
                                                      b_mod, wfrag, wauxf, baux);
    dcn_fused<<<dim3(2304), dim3(256), 0, stream>>>(x, wfrag, wauxf, baux, b, out);
}